// Round 2
// baseline (577.965 us; speedup 1.0000x reference)
//
#include <hip/hip_runtime.h>
#include <hip/hip_bf16.h>
#include <cstdint>

#define NND 100000
#define NED 1600000
#define FIN 128
#define FOUT 64

// bucket-sort CSR parameters
#define NBLK 512              // histogram/scatter blocks
#define EPB (NED / NBLK)      // 3125 edges per block (exact)
#define NBUCK 256             // coarse buckets
#define BSH 9                 // bucket = dst >> 9
#define BNODES 512            // nodes per bucket
#define HTN (NBUCK * NBLK)    // histT length = 131072

// feature-slice parameters: 8 slices of 16 channels, slice s pinned to XCD s
// layout: feat[slice][node][16ch] bf16  (32 B per node-slice row)
#define NSLICE 8
#define AGGC 2048             // node-chunks per slice; grid = AGGC*8

typedef __bf16 bf16x8 __attribute__((ext_vector_type(8)));
typedef float f32x4 __attribute__((ext_vector_type(4)));

static __device__ inline unsigned short f2bf(float f) {
    unsigned int u = __builtin_bit_cast(unsigned int, f);
    unsigned int r = (u + 0x7fffu + ((u >> 16) & 1u)) >> 16;  // RNE
    return (unsigned short)r;
}
static __device__ inline float bflo(unsigned int v) {
    return __builtin_bit_cast(float, v << 16);
}
static __device__ inline float bfhi(unsigned int v) {
    return __builtin_bit_cast(float, v & 0xffff0000u);
}
static __device__ inline float bf1(unsigned short u) {
    return __builtin_bit_cast(float, (unsigned int)u << 16);
}

// ---------------- weight pack into MFMA B-fragment order ----------------
static __device__ inline void pack_one(const float* __restrict__ W,
                                       unsigned short* __restrict__ out,
                                       int NTtot, int c_local, int nt,
                                       int chunkOff, int ncols, int lane) {
    int k = c_local * 32 + (lane >> 4) * 8;
    int n = nt * 16 + (lane & 15);
    unsigned short t[8];
#pragma unroll
    for (int j = 0; j < 8; j++) t[j] = f2bf(W[(size_t)(k + j) * ncols + n]);
    uint4 u;
    u.x = t[0] | ((unsigned)t[1] << 16);
    u.y = t[2] | ((unsigned)t[3] << 16);
    u.z = t[4] | ((unsigned)t[5] << 16);
    u.w = t[6] | ((unsigned)t[7] << 16);
    *(uint4*)&out[((size_t)((c_local + chunkOff) * NTtot + nt) * 64 + lane) * 8] = u;
}

// ---------------- K1: per-block bucket histogram + x cast + weight pack ----
// cast writes SLICE-MAJOR xb: xb[(s*N + node)*16 + ch16]
__global__ __launch_bounds__(256) void k_hist_cast(
        const int* __restrict__ dst, int* __restrict__ histT,
        const float* __restrict__ x, unsigned int* __restrict__ xb,
        const float* W1l, const float* W1r, const float* W2l,
        const float* W2r, const float* Wlin,
        unsigned short* p1, unsigned short* p2, unsigned short* ph) {
    __shared__ int hist[NBUCK];
    const int tid = threadIdx.x, blk = blockIdx.x;
    hist[tid] = 0;  // 256 threads == NBUCK
    __syncthreads();
    const int e0 = blk * EPB, e1 = e0 + EPB;
    for (int i = e0 + tid; i < e1; i += 256)
        atomicAdd(&hist[dst[i] >> BSH], 1);   // LDS atomic
    __syncthreads();
    histT[tid * NBLK + blk] = hist[tid];
    // fused weight pack (blocks 0..143, first wave)
    if (blk < 144 && tid < 64) {
        int b = blk, lane = tid;
        if (b < 32)       pack_one(W1l, p1, 8, b >> 3, b & 7, 0, 128, lane);
        else if (b < 64)  { b -= 32; pack_one(W1r, p1, 8, b >> 3, b & 7, 4, 128, lane); }
        else if (b < 96)  { b -= 64; pack_one(W2l, p2, 8, b >> 3, b & 7, 0, 128, lane); }
        else if (b < 128) { b -= 96; pack_one(W2r, p2, 8, b >> 3, b & 7, 4, 128, lane); }
        else              { b -= 128; pack_one(Wlin, ph, 4, b >> 2, b & 3, 0, 64, lane); }
    }
    // fused cast: j = (s*N + node)*4 + part  (uint2 = 4 channels)
    const int total = NND * 32;
    for (int j = blk * 256 + tid; j < total; j += NBLK * 256) {
        int sNode = j >> 2;
        int part = j & 3;
        int s = sNode / NND;
        int node = sNode - s * NND;
        float4 v = ((const float4*)x)[node * 32 + s * 4 + part];
        uint2 o;
        o.x = (unsigned)f2bf(v.x) | ((unsigned)f2bf(v.y) << 16);
        o.y = (unsigned)f2bf(v.z) | ((unsigned)f2bf(v.w) << 16);
        ((uint2*)xb)[j] = o;
    }
}

// ---------------- generic hierarchical exclusive scan (n = HTN) ------------
__global__ __launch_bounds__(1024) void g_scan1(const int* __restrict__ in,
                                                int* __restrict__ psum, int n) {
    __shared__ int red[1024];
    int tid = threadIdx.x;
    int i = blockIdx.x * 1024 + tid;
    red[tid] = (i < n) ? in[i] : 0;
    __syncthreads();
#pragma unroll
    for (int off = 512; off > 0; off >>= 1) {
        if (tid < off) red[tid] += red[tid + off];
        __syncthreads();
    }
    if (tid == 0) psum[blockIdx.x] = red[0];
}

__global__ __launch_bounds__(128) void g_scan2(int* __restrict__ psum, int nb) {
    int tid = threadIdx.x;
    int d = (tid < nb) ? psum[tid] : 0;
    int v = d;
#pragma unroll
    for (int off = 1; off < 64; off <<= 1) {
        int u = __shfl_up(v, off, 64);
        if ((tid & 63) >= off) v += u;
    }
    __shared__ int ws[2];
    if ((tid & 63) == 63) ws[tid >> 6] = v;
    __syncthreads();
    int base = (tid >= 64) ? ws[0] : 0;
    if (tid < nb) psum[tid] = base + v - d;
}

__global__ __launch_bounds__(1024) void g_scan3(const int* __restrict__ in,
                                                const int* __restrict__ psum,
                                                int* __restrict__ out, int n) {
    int tid = threadIdx.x;
    int i = blockIdx.x * 1024 + tid;
    int d = (i < n) ? in[i] : 0;
    int v = d;
#pragma unroll
    for (int off = 1; off < 64; off <<= 1) {
        int u = __shfl_up(v, off, 64);
        if ((tid & 63) >= off) v += u;
    }
    __shared__ int wsum[16];
    int wid = tid >> 6;
    if ((tid & 63) == 63) wsum[wid] = v;
    __syncthreads();
    if (tid < 16) {
        int w = wsum[tid];
#pragma unroll
        for (int off = 1; off < 16; off <<= 1) {
            int u = __shfl_up(w, off, 64);
            if (tid >= off) w += u;
        }
        wsum[tid] = w;
    }
    __syncthreads();
    int base = psum[blockIdx.x] + (wid ? wsum[wid - 1] : 0);
    if (i < n) out[i] = base + v - d;
}

// ---------------- K3: coarse scatter into bucket-grouped pairs -------------
__global__ __launch_bounds__(256) void k_scatter(const int* __restrict__ src,
                                                 const int* __restrict__ dst,
                                                 const int* __restrict__ sh,
                                                 uint2* __restrict__ eS) {
    __shared__ int cur[NBUCK];
    const int tid = threadIdx.x, blk = blockIdx.x;
    cur[tid] = sh[tid * NBLK + blk];
    __syncthreads();
    const int e0 = blk * EPB, e1 = e0 + EPB;
    for (int i = e0 + tid; i < e1; i += 256) {
        int d = dst[i];
        int pos = atomicAdd(&cur[d >> BSH], 1);   // LDS atomic
        eS[pos] = make_uint2((unsigned)src[i], (unsigned)(d & (BNODES - 1)));
    }
}

// ---------------- K4: per-bucket counting sort -> csr, offs, dinv ----------
__global__ __launch_bounds__(1024) void k_bucket(const uint2* __restrict__ eS,
                                                 const int* __restrict__ sh,
                                                 int* __restrict__ csr,
                                                 int* __restrict__ offs,
                                                 float* __restrict__ dinv, int n) {
    __shared__ int cnt[BNODES];
    __shared__ int loc[BNODES];
    const int b = blockIdx.x, tid = threadIdx.x;
    const int base = sh[b * NBLK];
    const int end = (b == NBUCK - 1) ? NED : sh[(b + 1) * NBLK];
    if (tid < BNODES) cnt[tid] = 0;
    __syncthreads();
    for (int i = base + tid; i < end; i += 1024)
        atomicAdd(&cnt[eS[i].y], 1);              // LDS atomic
    __syncthreads();
    // inclusive Hillis-Steele scan of cnt -> loc
    if (tid < BNODES) loc[tid] = cnt[tid];
    __syncthreads();
#pragma unroll
    for (int off = 1; off < BNODES; off <<= 1) {
        int v = 0;
        if (tid < BNODES && tid >= off) v = loc[tid - off];
        __syncthreads();
        if (tid < BNODES) loc[tid] += v;
        __syncthreads();
    }
    int node = b * BNODES + tid;
    int myExcl = 0;
    if (tid < BNODES) {
        myExcl = loc[tid] - cnt[tid];  // exclusive
        if (node < n) {
            offs[node] = base + myExcl;
            dinv[node] = 1.0f / fmaxf((float)cnt[tid], 1.0f);
        }
    }
    __syncthreads();
    if (tid < BNODES) cnt[tid] = base + myExcl;  // running cursor
    __syncthreads();
    for (int i = base + tid; i < end; i += 1024) {
        uint2 e = eS[i];
        int slot = atomicAdd(&cnt[e.y], 1);       // LDS atomic
        csr[slot] = (int)e.x;
    }
    if (b == 0 && tid == 0) offs[n] = NED;
}

// ---------------- mean-aggregate, XCD-sliced --------------------------------
// slice s = blockIdx&7 -> lands on XCD s (round-robin dispatch). Per-XCD
// gather working set = N*32B = 3.2 MB < 4 MB L2 -> gathers become L2 hits.
// Wave: 16 groups of 4 lanes; each group gathers one edge's 32B slice row.
__global__ __launch_bounds__(256) void k_aggb(const unsigned short* __restrict__ featS,
                                              const int* __restrict__ offs,
                                              const int* __restrict__ csr,
                                              const float* __restrict__ dinv,
                                              unsigned short* __restrict__ outS, int n) {
    const int s = blockIdx.x & 7;
    const int wid0 = (blockIdx.x >> 3) * 4 + (threadIdx.x >> 6);
    const int lane = threadIdx.x & 63;
    const int g = lane >> 2;   // edge group 0..15
    const int q = lane & 3;    // uint2 within 32B row (4 channels)
    const uint2* fS = (const uint2*)featS + (size_t)s * n * 4;
    uint2* oS = (uint2*)outS + (size_t)s * n * 4;

    for (int node = wid0; node < n; node += AGGC * 4) {
        const int beg = offs[node], end = offs[node + 1];
        const int deg = end - beg;
        const int full = beg + (deg & ~15);
        f32x4 acc = (f32x4){0.f, 0.f, 0.f, 0.f};
        // tail block first (address known up-front; overlaps with main loop)
        {
            int e = full + g;
            if (e < end) {
                uint2 v = fS[(size_t)csr[e] * 4 + q];
                acc.x += bflo(v.x); acc.y += bfhi(v.x);
                acc.z += bflo(v.y); acc.w += bfhi(v.y);
            }
        }
        for (int i = beg; i < full; i += 16) {
            int s0 = csr[i + g];
            uint2 v = fS[(size_t)s0 * 4 + q];
            acc.x += bflo(v.x); acc.y += bfhi(v.x);
            acc.z += bflo(v.y); acc.w += bfhi(v.y);
        }
        // reduce across the 16 groups (lane-xor 4,8,16,32)
#pragma unroll
        for (int m = 4; m <= 32; m <<= 1) {
            acc.x += __shfl_xor(acc.x, m);
            acc.y += __shfl_xor(acc.y, m);
            acc.z += __shfl_xor(acc.z, m);
            acc.w += __shfl_xor(acc.w, m);
        }
        if (g == 0) {
            float di = dinv[node];
            uint2 o;
            o.x = (unsigned)f2bf(acc.x * di) | ((unsigned)f2bf(acc.y * di) << 16);
            o.y = (unsigned)f2bf(acc.z * di) | ((unsigned)f2bf(acc.w * di) << 16);
            oS[(size_t)node * 4 + q] = o;
        }
    }
}

// ---------------- MFMA GEMM (+optional fused head), slice-major A ----------
template <int NT, int KCH, bool TWO, bool RELU, bool RESID, bool HEAD, bool OUTBF>
__global__ __launch_bounds__(256) void k_mfma(const unsigned short* __restrict__ P,
                                              const unsigned short* __restrict__ Q,
                                              const unsigned short* __restrict__ Wp,
                                              const float* __restrict__ bias,
                                              const unsigned short* __restrict__ resid,
                                              const unsigned short* __restrict__ Wp2,
                                              const float* __restrict__ bias2,
                                              void* __restrict__ outv, int n) {
    const int lane = threadIdx.x & 63;
    const int wave = threadIdx.x >> 6;
    const int quad = lane >> 4;
    const int row0 = blockIdx.x * 64 + wave * 16;
    int rowA = row0 + (lane & 15);
    if (rowA >= n) rowA = n - 1;

    f32x4 acc[NT];
#pragma unroll
    for (int t = 0; t < NT; t++) acc[t] = (f32x4){0.f, 0.f, 0.f, 0.f};

#pragma unroll
    for (int c = 0; c < KCH; c++) {
        const unsigned short* Abase = (TWO && c >= KCH / 2) ? Q : P;
        const int kk = (TWO ? (c & (KCH / 2 - 1)) : c) * 32 + quad * 8;
        // slice-major: channel kk -> slice kk>>4, offset kk&15
        bf16x8 a = *(const bf16x8*)&Abase[((size_t)(kk >> 4) * NND + rowA) * 16 + (kk & 15)];
#pragma unroll
        for (int t = 0; t < NT; t++) {
            bf16x8 b = *(const bf16x8*)&Wp[(size_t)((c * NT + t) * 64 + lane) * 8];
            acc[t] = __builtin_amdgcn_mfma_f32_16x16x32_bf16(a, b, acc[t], 0, 0, 0);
        }
    }

    const int col = lane & 15;
    if (!HEAD) {
#pragma unroll
        for (int t = 0; t < NT; t++) {
            float bv = bias[t * 16 + col];
#pragma unroll
            for (int r = 0; r < 4; r++) {
                int row = row0 + quad * 4 + r;
                if (row < n) {
                    float v = acc[t][r] + bv;
                    if (RESID) v += bf1(resid[((size_t)t * NND + row) * 16 + col]);
                    if (RELU) v = fmaxf(v, 0.f);
                    if (OUTBF)  // slice-major: output slice = t
                        ((unsigned short*)outv)[((size_t)t * NND + row) * 16 + col] = f2bf(v);
                    else
                        ((float*)outv)[(size_t)row * (NT * 16) + t * 16 + col] = v;
                }
            }
        }
    } else {
        __shared__ __align__(16) unsigned short sT[4][16 * 136];
#pragma unroll
        for (int t = 0; t < NT; t++) {
            float bv = bias[t * 16 + col];
#pragma unroll
            for (int r = 0; r < 4; r++) {
                int row = row0 + quad * 4 + r;
                int rr = row < n ? row : n - 1;
                float v = acc[t][r] + bv;
                if (RESID) v += bf1(resid[((size_t)t * NND + rr) * 16 + col]);
                if (RELU) v = fmaxf(v, 0.f);
                sT[wave][(quad * 4 + r) * 136 + t * 16 + col] = f2bf(v);
            }
        }
        f32x4 hacc[4];
#pragma unroll
        for (int t = 0; t < 4; t++) hacc[t] = (f32x4){0.f, 0.f, 0.f, 0.f};
#pragma unroll
        for (int c = 0; c < 4; c++) {
            bf16x8 a = *(const bf16x8*)&sT[wave][(lane & 15) * 136 + c * 32 + quad * 8];
#pragma unroll
            for (int t = 0; t < 4; t++) {
                bf16x8 b = *(const bf16x8*)&Wp2[(size_t)((c * 4 + t) * 64 + lane) * 8];
                hacc[t] = __builtin_amdgcn_mfma_f32_16x16x32_bf16(a, b, hacc[t], 0, 0, 0);
            }
        }
#pragma unroll
        for (int t = 0; t < 4; t++) {
            float bv = bias2[t * 16 + col];
#pragma unroll
            for (int r = 0; r < 4; r++) {
                int row = row0 + quad * 4 + r;
                if (row < n)
                    ((float*)outv)[(size_t)row * 64 + t * 16 + col] = hacc[t][r] + bv;
            }
        }
    }
}

extern "C" void kernel_launch(void* const* d_in, const int* in_sizes, int n_in,
                              void* d_out, int out_size, void* d_ws, size_t ws_size,
                              hipStream_t stream) {
    const float* x    = (const float*)d_in[0];
    const int*   ei   = (const int*)d_in[1];
    const float* W1l  = (const float*)d_in[2];
    const float* b1   = (const float*)d_in[3];
    const float* W1r  = (const float*)d_in[4];
    const float* W2l  = (const float*)d_in[5];
    const float* b2   = (const float*)d_in[6];
    const float* W2r  = (const float*)d_in[7];
    const float* Wlin = (const float*)d_in[8];
    const float* blin = (const float*)d_in[9];
    float* out = (float*)d_out;

    const int N = NND, E = NED;
    const int* src = ei;
    const int* dst = ei + E;
    const int NB2 = HTN / 1024;  // 128 scan blocks

    char* w = (char*)d_ws;
    int*   histT  = (int*)w;               w += (size_t)HTN * 4;
    int*   sh     = (int*)w;               w += (size_t)HTN * 4;
    int*   psum   = (int*)w;               w += (size_t)NB2 * 4;
    int*   offs   = (int*)w;               w += (size_t)(N + 4) * 4;
    float* dinv   = (float*)w;             w += (size_t)N * 4;
    uint2* eS     = (uint2*)w;             w += (size_t)E * 8;
    int*   csr    = (int*)w;               w += (size_t)E * 4;
    unsigned short* p1  = (unsigned short*)w;  w += 256 * 128 * 2;
    unsigned short* p2  = (unsigned short*)w;  w += 256 * 128 * 2;
    unsigned short* ph  = (unsigned short*)w;  w += 128 * 64 * 2;
    unsigned short* xb  = (unsigned short*)w;  w += (size_t)N * 128 * 2;
    unsigned short* agg = (unsigned short*)w;  w += (size_t)N * 128 * 2;
    unsigned short* h1  = (unsigned short*)w;  w += (size_t)N * 128 * 2;

    // CSR build: zero global atomics
    k_hist_cast<<<NBLK, 256, 0, stream>>>(dst, histT, x, (unsigned int*)xb,
                                          W1l, W1r, W2l, W2r, Wlin, p1, p2, ph);
    g_scan1<<<NB2, 1024, 0, stream>>>(histT, psum, HTN);
    g_scan2<<<1, 128, 0, stream>>>(psum, NB2);
    g_scan3<<<NB2, 1024, 0, stream>>>(histT, psum, sh, HTN);
    k_scatter<<<NBLK, 256, 0, stream>>>(src, dst, sh, eS);
    k_bucket<<<NBUCK, 1024, 0, stream>>>(eS, sh, csr, offs, dinv, N);

    // layer 1: h1 = relu([agg|xb] @ [W1l;W1r] + b1)
    k_aggb<<<AGGC * 8, 256, 0, stream>>>(xb, offs, csr, dinv, agg, N);
    k_mfma<8, 8, true, true, false, false, true><<<(N + 63) / 64, 256, 0, stream>>>(
        agg, xb, p1, b1, nullptr, nullptr, nullptr, h1, N);

    // layer 2 + head fused
    k_aggb<<<AGGC * 8, 256, 0, stream>>>(h1, offs, csr, dinv, agg, N);
    k_mfma<8, 8, true, true, true, true, false><<<(N + 63) / 64, 256, 0, stream>>>(
        agg, h1, p2, b2, h1, ph, blin, out, N);
}

// Round 3
// 473.386 us; speedup vs baseline: 1.2209x; 1.2209x over previous
//
#include <hip/hip_runtime.h>
#include <hip/hip_bf16.h>
#include <cstdint>

#define NND 100000
#define NED 1600000
#define FIN 128
#define FOUT 64

// bucket-sort CSR parameters
#define NBLK 512              // histogram/scatter blocks
#define EPB (NED / NBLK)      // 3125 edges per block (exact)
#define NBUCK 256             // coarse buckets
#define BSH 9                 // bucket = dst >> 9
#define BNODES 512            // nodes per bucket
#define HTN (NBUCK * NBLK)    // histT length = 131072

// feature-slice parameters: 8 slices of 16 channels, slice s pinned to XCD s
// layout: feat[slice][node][16ch] bf16  (32 B per node-slice row)
#define NSLICE 8
#define AGGCH 1563            // chunks per slice; grid = AGGCH*8, 16 nodes/wave

typedef __bf16 bf16x8 __attribute__((ext_vector_type(8)));
typedef float f32x4 __attribute__((ext_vector_type(4)));

static __device__ inline unsigned short f2bf(float f) {
    unsigned int u = __builtin_bit_cast(unsigned int, f);
    unsigned int r = (u + 0x7fffu + ((u >> 16) & 1u)) >> 16;  // RNE
    return (unsigned short)r;
}
static __device__ inline float bflo(unsigned int v) {
    return __builtin_bit_cast(float, v << 16);
}
static __device__ inline float bfhi(unsigned int v) {
    return __builtin_bit_cast(float, v & 0xffff0000u);
}
static __device__ inline float bf1(unsigned short u) {
    return __builtin_bit_cast(float, (unsigned int)u << 16);
}

// ---------------- weight pack into MFMA B-fragment order ----------------
static __device__ inline void pack_one(const float* __restrict__ W,
                                       unsigned short* __restrict__ out,
                                       int NTtot, int c_local, int nt,
                                       int chunkOff, int ncols, int lane) {
    int k = c_local * 32 + (lane >> 4) * 8;
    int n = nt * 16 + (lane & 15);
    unsigned short t[8];
#pragma unroll
    for (int j = 0; j < 8; j++) t[j] = f2bf(W[(size_t)(k + j) * ncols + n]);
    uint4 u;
    u.x = t[0] | ((unsigned)t[1] << 16);
    u.y = t[2] | ((unsigned)t[3] << 16);
    u.z = t[4] | ((unsigned)t[5] << 16);
    u.w = t[6] | ((unsigned)t[7] << 16);
    *(uint4*)&out[((size_t)((c_local + chunkOff) * NTtot + nt) * 64 + lane) * 8] = u;
}

// ---------------- K1: per-block bucket histogram + x cast + weight pack ----
// cast writes SLICE-MAJOR xb: xb[(s*N + node)*16 + ch16]
__global__ __launch_bounds__(256) void k_hist_cast(
        const int* __restrict__ dst, int* __restrict__ histT,
        const float* __restrict__ x, unsigned int* __restrict__ xb,
        const float* W1l, const float* W1r, const float* W2l,
        const float* W2r, const float* Wlin,
        unsigned short* p1, unsigned short* p2, unsigned short* ph) {
    __shared__ int hist[NBUCK];
    const int tid = threadIdx.x, blk = blockIdx.x;
    hist[tid] = 0;  // 256 threads == NBUCK
    __syncthreads();
    const int e0 = blk * EPB, e1 = e0 + EPB;
    for (int i = e0 + tid; i < e1; i += 256)
        atomicAdd(&hist[dst[i] >> BSH], 1);   // LDS atomic
    __syncthreads();
    histT[tid * NBLK + blk] = hist[tid];
    // fused weight pack (blocks 0..143, first wave)
    if (blk < 144 && tid < 64) {
        int b = blk, lane = tid;
        if (b < 32)       pack_one(W1l, p1, 8, b >> 3, b & 7, 0, 128, lane);
        else if (b < 64)  { b -= 32; pack_one(W1r, p1, 8, b >> 3, b & 7, 4, 128, lane); }
        else if (b < 96)  { b -= 64; pack_one(W2l, p2, 8, b >> 3, b & 7, 0, 128, lane); }
        else if (b < 128) { b -= 96; pack_one(W2r, p2, 8, b >> 3, b & 7, 4, 128, lane); }
        else              { b -= 128; pack_one(Wlin, ph, 4, b >> 2, b & 3, 0, 64, lane); }
    }
    // fused cast: j = (s*N + node)*4 + part  (uint2 = 4 channels)
    const int total = NND * 32;
    for (int j = blk * 256 + tid; j < total; j += NBLK * 256) {
        int sNode = j >> 2;
        int part = j & 3;
        int s = sNode / NND;
        int node = sNode - s * NND;
        float4 v = ((const float4*)x)[node * 32 + s * 4 + part];
        uint2 o;
        o.x = (unsigned)f2bf(v.x) | ((unsigned)f2bf(v.y) << 16);
        o.y = (unsigned)f2bf(v.z) | ((unsigned)f2bf(v.w) << 16);
        ((uint2*)xb)[j] = o;
    }
}

// ---------------- generic hierarchical exclusive scan (n = HTN) ------------
__global__ __launch_bounds__(1024) void g_scan1(const int* __restrict__ in,
                                                int* __restrict__ psum, int n) {
    __shared__ int red[1024];
    int tid = threadIdx.x;
    int i = blockIdx.x * 1024 + tid;
    red[tid] = (i < n) ? in[i] : 0;
    __syncthreads();
#pragma unroll
    for (int off = 512; off > 0; off >>= 1) {
        if (tid < off) red[tid] += red[tid + off];
        __syncthreads();
    }
    if (tid == 0) psum[blockIdx.x] = red[0];
}

__global__ __launch_bounds__(128) void g_scan2(int* __restrict__ psum, int nb) {
    int tid = threadIdx.x;
    int d = (tid < nb) ? psum[tid] : 0;
    int v = d;
#pragma unroll
    for (int off = 1; off < 64; off <<= 1) {
        int u = __shfl_up(v, off, 64);
        if ((tid & 63) >= off) v += u;
    }
    __shared__ int ws[2];
    if ((tid & 63) == 63) ws[tid >> 6] = v;
    __syncthreads();
    int base = (tid >= 64) ? ws[0] : 0;
    if (tid < nb) psum[tid] = base + v - d;
}

__global__ __launch_bounds__(1024) void g_scan3(const int* __restrict__ in,
                                                const int* __restrict__ psum,
                                                int* __restrict__ out, int n) {
    int tid = threadIdx.x;
    int i = blockIdx.x * 1024 + tid;
    int d = (i < n) ? in[i] : 0;
    int v = d;
#pragma unroll
    for (int off = 1; off < 64; off <<= 1) {
        int u = __shfl_up(v, off, 64);
        if ((tid & 63) >= off) v += u;
    }
    __shared__ int wsum[16];
    int wid = tid >> 6;
    if ((tid & 63) == 63) wsum[wid] = v;
    __syncthreads();
    if (tid < 16) {
        int w = wsum[tid];
#pragma unroll
        for (int off = 1; off < 16; off <<= 1) {
            int u = __shfl_up(w, off, 64);
            if (tid >= off) w += u;
        }
        wsum[tid] = w;
    }
    __syncthreads();
    int base = psum[blockIdx.x] + (wid ? wsum[wid - 1] : 0);
    if (i < n) out[i] = base + v - d;
}

// ---------------- K3: coarse scatter into bucket-grouped pairs -------------
__global__ __launch_bounds__(256) void k_scatter(const int* __restrict__ src,
                                                 const int* __restrict__ dst,
                                                 const int* __restrict__ sh,
                                                 uint2* __restrict__ eS) {
    __shared__ int cur[NBUCK];
    const int tid = threadIdx.x, blk = blockIdx.x;
    cur[tid] = sh[tid * NBLK + blk];
    __syncthreads();
    const int e0 = blk * EPB, e1 = e0 + EPB;
    for (int i = e0 + tid; i < e1; i += 256) {
        int d = dst[i];
        int pos = atomicAdd(&cur[d >> BSH], 1);   // LDS atomic
        eS[pos] = make_uint2((unsigned)src[i], (unsigned)(d & (BNODES - 1)));
    }
}

// ---------------- K4: per-bucket counting sort -> csr, offs, dinv ----------
__global__ __launch_bounds__(1024) void k_bucket(const uint2* __restrict__ eS,
                                                 const int* __restrict__ sh,
                                                 int* __restrict__ csr,
                                                 int* __restrict__ offs,
                                                 float* __restrict__ dinv, int n) {
    __shared__ int cnt[BNODES];
    __shared__ int loc[BNODES];
    const int b = blockIdx.x, tid = threadIdx.x;
    const int base = sh[b * NBLK];
    const int end = (b == NBUCK - 1) ? NED : sh[(b + 1) * NBLK];
    if (tid < BNODES) cnt[tid] = 0;
    __syncthreads();
    for (int i = base + tid; i < end; i += 1024)
        atomicAdd(&cnt[eS[i].y], 1);              // LDS atomic
    __syncthreads();
    // inclusive Hillis-Steele scan of cnt -> loc
    if (tid < BNODES) loc[tid] = cnt[tid];
    __syncthreads();
#pragma unroll
    for (int off = 1; off < BNODES; off <<= 1) {
        int v = 0;
        if (tid < BNODES && tid >= off) v = loc[tid - off];
        __syncthreads();
        if (tid < BNODES) loc[tid] += v;
        __syncthreads();
    }
    int node = b * BNODES + tid;
    int myExcl = 0;
    if (tid < BNODES) {
        myExcl = loc[tid] - cnt[tid];  // exclusive
        if (node < n) {
            offs[node] = base + myExcl;
            dinv[node] = 1.0f / fmaxf((float)cnt[tid], 1.0f);
        }
    }
    __syncthreads();
    if (tid < BNODES) cnt[tid] = base + myExcl;  // running cursor
    __syncthreads();
    for (int i = base + tid; i < end; i += 1024) {
        uint2 e = eS[i];
        int slot = atomicAdd(&cnt[e.y], 1);       // LDS atomic
        csr[slot] = (int)e.x;
    }
    if (b == 0 && tid == 0) offs[n] = NED;
}

// ---------------- mean-aggregate, XCD-sliced, group-per-node ----------------
// slice s = blockIdx&7 -> XCD s; per-XCD table slice 3.2 MB stays L2-resident
// (proven R2: FETCH 257->47 MB). NEW: 16 groups of 4 lanes; group g owns node
// base+g and accumulates its 4 channels in registers. No cross-lane reduce,
// coalesced offs loads and stores, 16 independent gather chains per wave.
__global__ __launch_bounds__(256) void k_aggb(const unsigned short* __restrict__ featS,
                                              const int* __restrict__ offs,
                                              const int* __restrict__ csr,
                                              const float* __restrict__ dinv,
                                              unsigned short* __restrict__ outS, int n) {
    const int s = blockIdx.x & 7;
    const int wslot = (blockIdx.x >> 3) * 4 + (threadIdx.x >> 6);
    const int lane = threadIdx.x & 63;
    const int g = lane >> 2;   // group 0..15, one node each
    const int q = lane & 3;    // uint2 within 32B row (4 channels)
    const uint2* fS = (const uint2*)featS + (size_t)s * n * 4;
    uint2* oS = (uint2*)outS + (size_t)s * n * 4;

    for (int base = wslot * 16; base < n; base += AGGCH * 4 * 16) {
        const int node = base + g;
        const bool valid = node < n;
        const int beg = valid ? offs[node] : 0;
        const int end = valid ? offs[node + 1] : 0;
        f32x4 acc = (f32x4){0.f, 0.f, 0.f, 0.f};
        for (int e = beg; e < end; e++) {
            unsigned si = (unsigned)csr[e];
            uint2 v = fS[si * 4u + q];
            acc.x += bflo(v.x); acc.y += bfhi(v.x);
            acc.z += bflo(v.y); acc.w += bfhi(v.y);
        }
        if (valid) {
            float di = dinv[node];
            uint2 o;
            o.x = (unsigned)f2bf(acc.x * di) | ((unsigned)f2bf(acc.y * di) << 16);
            o.y = (unsigned)f2bf(acc.z * di) | ((unsigned)f2bf(acc.w * di) << 16);
            oS[(size_t)node * 4 + q] = o;
        }
    }
}

// ---------------- MFMA GEMM (+optional fused head), slice-major A ----------
template <int NT, int KCH, bool TWO, bool RELU, bool RESID, bool HEAD, bool OUTBF>
__global__ __launch_bounds__(256) void k_mfma(const unsigned short* __restrict__ P,
                                              const unsigned short* __restrict__ Q,
                                              const unsigned short* __restrict__ Wp,
                                              const float* __restrict__ bias,
                                              const unsigned short* __restrict__ resid,
                                              const unsigned short* __restrict__ Wp2,
                                              const float* __restrict__ bias2,
                                              void* __restrict__ outv, int n) {
    const int lane = threadIdx.x & 63;
    const int wave = threadIdx.x >> 6;
    const int quad = lane >> 4;
    const int row0 = blockIdx.x * 64 + wave * 16;
    int rowA = row0 + (lane & 15);
    if (rowA >= n) rowA = n - 1;

    f32x4 acc[NT];
#pragma unroll
    for (int t = 0; t < NT; t++) acc[t] = (f32x4){0.f, 0.f, 0.f, 0.f};

#pragma unroll
    for (int c = 0; c < KCH; c++) {
        const unsigned short* Abase = (TWO && c >= KCH / 2) ? Q : P;
        const int kk = (TWO ? (c & (KCH / 2 - 1)) : c) * 32 + quad * 8;
        // slice-major: channel kk -> slice kk>>4, offset kk&15
        bf16x8 a = *(const bf16x8*)&Abase[((size_t)(kk >> 4) * NND + rowA) * 16 + (kk & 15)];
#pragma unroll
        for (int t = 0; t < NT; t++) {
            bf16x8 b = *(const bf16x8*)&Wp[(size_t)((c * NT + t) * 64 + lane) * 8];
            acc[t] = __builtin_amdgcn_mfma_f32_16x16x32_bf16(a, b, acc[t], 0, 0, 0);
        }
    }

    const int col = lane & 15;
    if (!HEAD) {
#pragma unroll
        for (int t = 0; t < NT; t++) {
            float bv = bias[t * 16 + col];
#pragma unroll
            for (int r = 0; r < 4; r++) {
                int row = row0 + quad * 4 + r;
                if (row < n) {
                    float v = acc[t][r] + bv;
                    if (RESID) v += bf1(resid[((size_t)t * NND + row) * 16 + col]);
                    if (RELU) v = fmaxf(v, 0.f);
                    if (OUTBF)  // slice-major: output slice = t
                        ((unsigned short*)outv)[((size_t)t * NND + row) * 16 + col] = f2bf(v);
                    else
                        ((float*)outv)[(size_t)row * (NT * 16) + t * 16 + col] = v;
                }
            }
        }
    } else {
        __shared__ __align__(16) unsigned short sT[4][16 * 136];
#pragma unroll
        for (int t = 0; t < NT; t++) {
            float bv = bias[t * 16 + col];
#pragma unroll
            for (int r = 0; r < 4; r++) {
                int row = row0 + quad * 4 + r;
                int rr = row < n ? row : n - 1;
                float v = acc[t][r] + bv;
                if (RESID) v += bf1(resid[((size_t)t * NND + rr) * 16 + col]);
                if (RELU) v = fmaxf(v, 0.f);
                sT[wave][(quad * 4 + r) * 136 + t * 16 + col] = f2bf(v);
            }
        }
        f32x4 hacc[4];
#pragma unroll
        for (int t = 0; t < 4; t++) hacc[t] = (f32x4){0.f, 0.f, 0.f, 0.f};
#pragma unroll
        for (int c = 0; c < 4; c++) {
            bf16x8 a = *(const bf16x8*)&sT[wave][(lane & 15) * 136 + c * 32 + quad * 8];
#pragma unroll
            for (int t = 0; t < 4; t++) {
                bf16x8 b = *(const bf16x8*)&Wp2[(size_t)((c * 4 + t) * 64 + lane) * 8];
                hacc[t] = __builtin_amdgcn_mfma_f32_16x16x32_bf16(a, b, hacc[t], 0, 0, 0);
            }
        }
#pragma unroll
        for (int t = 0; t < 4; t++) {
            float bv = bias2[t * 16 + col];
#pragma unroll
            for (int r = 0; r < 4; r++) {
                int row = row0 + quad * 4 + r;
                if (row < n)
                    ((float*)outv)[(size_t)row * 64 + t * 16 + col] = hacc[t][r] + bv;
            }
        }
    }
}

extern "C" void kernel_launch(void* const* d_in, const int* in_sizes, int n_in,
                              void* d_out, int out_size, void* d_ws, size_t ws_size,
                              hipStream_t stream) {
    const float* x    = (const float*)d_in[0];
    const int*   ei   = (const int*)d_in[1];
    const float* W1l  = (const float*)d_in[2];
    const float* b1   = (const float*)d_in[3];
    const float* W1r  = (const float*)d_in[4];
    const float* W2l  = (const float*)d_in[5];
    const float* b2   = (const float*)d_in[6];
    const float* W2r  = (const float*)d_in[7];
    const float* Wlin = (const float*)d_in[8];
    const float* blin = (const float*)d_in[9];
    float* out = (float*)d_out;

    const int N = NND, E = NED;
    const int* src = ei;
    const int* dst = ei + E;
    const int NB2 = HTN / 1024;  // 128 scan blocks

    char* w = (char*)d_ws;
    int*   histT  = (int*)w;               w += (size_t)HTN * 4;
    int*   sh     = (int*)w;               w += (size_t)HTN * 4;
    int*   psum   = (int*)w;               w += (size_t)NB2 * 4;
    int*   offs   = (int*)w;               w += (size_t)(N + 4) * 4;
    float* dinv   = (float*)w;             w += (size_t)N * 4;
    uint2* eS     = (uint2*)w;             w += (size_t)E * 8;
    int*   csr    = (int*)w;               w += (size_t)E * 4;
    unsigned short* p1  = (unsigned short*)w;  w += 256 * 128 * 2;
    unsigned short* p2  = (unsigned short*)w;  w += 256 * 128 * 2;
    unsigned short* ph  = (unsigned short*)w;  w += 128 * 64 * 2;
    unsigned short* xb  = (unsigned short*)w;  w += (size_t)N * 128 * 2;
    unsigned short* agg = (unsigned short*)w;  w += (size_t)N * 128 * 2;
    unsigned short* h1  = (unsigned short*)w;  w += (size_t)N * 128 * 2;

    // CSR build: zero global atomics
    k_hist_cast<<<NBLK, 256, 0, stream>>>(dst, histT, x, (unsigned int*)xb,
                                          W1l, W1r, W2l, W2r, Wlin, p1, p2, ph);
    g_scan1<<<NB2, 1024, 0, stream>>>(histT, psum, HTN);
    g_scan2<<<1, 128, 0, stream>>>(psum, NB2);
    g_scan3<<<NB2, 1024, 0, stream>>>(histT, psum, sh, HTN);
    k_scatter<<<NBLK, 256, 0, stream>>>(src, dst, sh, eS);
    k_bucket<<<NBUCK, 1024, 0, stream>>>(eS, sh, csr, offs, dinv, N);

    // layer 1: h1 = relu([agg|xb] @ [W1l;W1r] + b1)
    k_aggb<<<AGGCH * 8, 256, 0, stream>>>(xb, offs, csr, dinv, agg, N);
    k_mfma<8, 8, true, true, false, false, true><<<(N + 63) / 64, 256, 0, stream>>>(
        agg, xb, p1, b1, nullptr, nullptr, nullptr, h1, N);

    // layer 2 + head fused
    k_aggb<<<AGGCH * 8, 256, 0, stream>>>(h1, offs, csr, dinv, agg, N);
    k_mfma<8, 8, true, true, true, true, false><<<(N + 63) / 64, 256, 0, stream>>>(
        agg, h1, p2, b2, h1, ph, blin, out, N);
}

// Round 4
// 403.469 us; speedup vs baseline: 1.4325x; 1.1733x over previous
//
#include <hip/hip_runtime.h>
#include <hip/hip_bf16.h>
#include <cstdint>

#define NND 100000
#define NED 1600000
#define FIN 128
#define FOUT 64

// bucket-sort CSR parameters
#define NBLK 512              // histogram/scatter blocks
#define EPB (NED / NBLK)      // 3125 edges per block (exact)
#define NBUCK 256             // coarse buckets
#define BSH 9                 // bucket = dst >> 9
#define BNODES 512            // nodes per bucket
#define HTN (NBUCK * NBLK)    // histT length = 131072

// feature-slice parameters: 8 slices of 16 channels, slice s pinned to XCD s
// layout: feat[slice][node][16ch] bf16  (32 B per node-slice row)
#define NSLICE 8
#define AGGCH 1563            // chunks per slice; grid = AGGCH*8, 16 nodes/wave

typedef __bf16 bf16x8 __attribute__((ext_vector_type(8)));
typedef float f32x4 __attribute__((ext_vector_type(4)));

static __device__ inline unsigned short f2bf(float f) {
    unsigned int u = __builtin_bit_cast(unsigned int, f);
    unsigned int r = (u + 0x7fffu + ((u >> 16) & 1u)) >> 16;  // RNE
    return (unsigned short)r;
}
static __device__ inline float bflo(unsigned int v) {
    return __builtin_bit_cast(float, v << 16);
}
static __device__ inline float bfhi(unsigned int v) {
    return __builtin_bit_cast(float, v & 0xffff0000u);
}
static __device__ inline float bf1(unsigned short u) {
    return __builtin_bit_cast(float, (unsigned int)u << 16);
}

// ---------------- weight pack into MFMA B-fragment order ----------------
static __device__ inline void pack_one(const float* __restrict__ W,
                                       unsigned short* __restrict__ out,
                                       int NTtot, int c_local, int nt,
                                       int chunkOff, int ncols, int lane) {
    int k = c_local * 32 + (lane >> 4) * 8;
    int n = nt * 16 + (lane & 15);
    unsigned short t[8];
#pragma unroll
    for (int j = 0; j < 8; j++) t[j] = f2bf(W[(size_t)(k + j) * ncols + n]);
    uint4 u;
    u.x = t[0] | ((unsigned)t[1] << 16);
    u.y = t[2] | ((unsigned)t[3] << 16);
    u.z = t[4] | ((unsigned)t[5] << 16);
    u.w = t[6] | ((unsigned)t[7] << 16);
    *(uint4*)&out[((size_t)((c_local + chunkOff) * NTtot + nt) * 64 + lane) * 8] = u;
}

// ---------------- K1: per-block bucket histogram + x cast + weight pack ----
// cast writes SLICE-MAJOR xb: xb[(s*N + node)*16 + ch16]
__global__ __launch_bounds__(256) void k_hist_cast(
        const int* __restrict__ dst, int* __restrict__ histT,
        const float* __restrict__ x, unsigned int* __restrict__ xb,
        const float* W1l, const float* W1r, const float* W2l,
        const float* W2r, const float* Wlin,
        unsigned short* p1, unsigned short* p2, unsigned short* ph) {
    __shared__ int hist[NBUCK];
    const int tid = threadIdx.x, blk = blockIdx.x;
    hist[tid] = 0;  // 256 threads == NBUCK
    __syncthreads();
    const int e0 = blk * EPB, e1 = e0 + EPB;
    for (int i = e0 + tid; i < e1; i += 256)
        atomicAdd(&hist[dst[i] >> BSH], 1);   // LDS atomic
    __syncthreads();
    histT[tid * NBLK + blk] = hist[tid];
    // fused weight pack (blocks 0..143, first wave)
    if (blk < 144 && tid < 64) {
        int b = blk, lane = tid;
        if (b < 32)       pack_one(W1l, p1, 8, b >> 3, b & 7, 0, 128, lane);
        else if (b < 64)  { b -= 32; pack_one(W1r, p1, 8, b >> 3, b & 7, 4, 128, lane); }
        else if (b < 96)  { b -= 64; pack_one(W2l, p2, 8, b >> 3, b & 7, 0, 128, lane); }
        else if (b < 128) { b -= 96; pack_one(W2r, p2, 8, b >> 3, b & 7, 4, 128, lane); }
        else              { b -= 128; pack_one(Wlin, ph, 4, b >> 2, b & 3, 0, 64, lane); }
    }
    // fused cast: j = (s*N + node)*4 + part  (uint2 = 4 channels)
    const int total = NND * 32;
    for (int j = blk * 256 + tid; j < total; j += NBLK * 256) {
        int sNode = j >> 2;
        int part = j & 3;
        int s = sNode / NND;
        int node = sNode - s * NND;
        float4 v = ((const float4*)x)[node * 32 + s * 4 + part];
        uint2 o;
        o.x = (unsigned)f2bf(v.x) | ((unsigned)f2bf(v.y) << 16);
        o.y = (unsigned)f2bf(v.z) | ((unsigned)f2bf(v.w) << 16);
        ((uint2*)xb)[j] = o;
    }
}

// ---------------- generic hierarchical exclusive scan (n = HTN) ------------
__global__ __launch_bounds__(1024) void g_scan1(const int* __restrict__ in,
                                                int* __restrict__ psum, int n) {
    __shared__ int red[1024];
    int tid = threadIdx.x;
    int i = blockIdx.x * 1024 + tid;
    red[tid] = (i < n) ? in[i] : 0;
    __syncthreads();
#pragma unroll
    for (int off = 512; off > 0; off >>= 1) {
        if (tid < off) red[tid] += red[tid + off];
        __syncthreads();
    }
    if (tid == 0) psum[blockIdx.x] = red[0];
}

__global__ __launch_bounds__(128) void g_scan2(int* __restrict__ psum, int nb) {
    int tid = threadIdx.x;
    int d = (tid < nb) ? psum[tid] : 0;
    int v = d;
#pragma unroll
    for (int off = 1; off < 64; off <<= 1) {
        int u = __shfl_up(v, off, 64);
        if ((tid & 63) >= off) v += u;
    }
    __shared__ int ws[2];
    if ((tid & 63) == 63) ws[tid >> 6] = v;
    __syncthreads();
    int base = (tid >= 64) ? ws[0] : 0;
    if (tid < nb) psum[tid] = base + v - d;
}

__global__ __launch_bounds__(1024) void g_scan3(const int* __restrict__ in,
                                                const int* __restrict__ psum,
                                                int* __restrict__ out, int n) {
    int tid = threadIdx.x;
    int i = blockIdx.x * 1024 + tid;
    int d = (i < n) ? in[i] : 0;
    int v = d;
#pragma unroll
    for (int off = 1; off < 64; off <<= 1) {
        int u = __shfl_up(v, off, 64);
        if ((tid & 63) >= off) v += u;
    }
    __shared__ int wsum[16];
    int wid = tid >> 6;
    if ((tid & 63) == 63) wsum[wid] = v;
    __syncthreads();
    if (tid < 16) {
        int w = wsum[tid];
#pragma unroll
        for (int off = 1; off < 16; off <<= 1) {
            int u = __shfl_up(w, off, 64);
            if (tid >= off) w += u;
        }
        wsum[tid] = w;
    }
    __syncthreads();
    int base = psum[blockIdx.x] + (wid ? wsum[wid - 1] : 0);
    if (i < n) out[i] = base + v - d;
}

// ---------------- K3: coarse scatter into bucket-grouped pairs -------------
__global__ __launch_bounds__(256) void k_scatter(const int* __restrict__ src,
                                                 const int* __restrict__ dst,
                                                 const int* __restrict__ sh,
                                                 uint2* __restrict__ eS) {
    __shared__ int cur[NBUCK];
    const int tid = threadIdx.x, blk = blockIdx.x;
    cur[tid] = sh[tid * NBLK + blk];
    __syncthreads();
    const int e0 = blk * EPB, e1 = e0 + EPB;
    for (int i = e0 + tid; i < e1; i += 256) {
        int d = dst[i];
        int pos = atomicAdd(&cur[d >> BSH], 1);   // LDS atomic
        eS[pos] = make_uint2((unsigned)src[i], (unsigned)(d & (BNODES - 1)));
    }
}

// ---------------- K4: per-bucket counting sort -> csr, offs, dinv ----------
__global__ __launch_bounds__(1024) void k_bucket(const uint2* __restrict__ eS,
                                                 const int* __restrict__ sh,
                                                 int* __restrict__ csr,
                                                 int* __restrict__ offs,
                                                 float* __restrict__ dinv, int n) {
    __shared__ int cnt[BNODES];
    __shared__ int loc[BNODES];
    const int b = blockIdx.x, tid = threadIdx.x;
    const int base = sh[b * NBLK];
    const int end = (b == NBUCK - 1) ? NED : sh[(b + 1) * NBLK];
    if (tid < BNODES) cnt[tid] = 0;
    __syncthreads();
    for (int i = base + tid; i < end; i += 1024)
        atomicAdd(&cnt[eS[i].y], 1);              // LDS atomic
    __syncthreads();
    // inclusive Hillis-Steele scan of cnt -> loc
    if (tid < BNODES) loc[tid] = cnt[tid];
    __syncthreads();
#pragma unroll
    for (int off = 1; off < BNODES; off <<= 1) {
        int v = 0;
        if (tid < BNODES && tid >= off) v = loc[tid - off];
        __syncthreads();
        if (tid < BNODES) loc[tid] += v;
        __syncthreads();
    }
    int node = b * BNODES + tid;
    int myExcl = 0;
    if (tid < BNODES) {
        myExcl = loc[tid] - cnt[tid];  // exclusive
        if (node < n) {
            offs[node] = base + myExcl;
            dinv[node] = 1.0f / fmaxf((float)cnt[tid], 1.0f);
        }
    }
    __syncthreads();
    if (tid < BNODES) cnt[tid] = base + myExcl;  // running cursor
    __syncthreads();
    for (int i = base + tid; i < end; i += 1024) {
        uint2 e = eS[i];
        int slot = atomicAdd(&cnt[e.y], 1);       // LDS atomic
        csr[slot] = (int)e.x;
    }
    if (b == 0 && tid == 0) offs[n] = NED;
}

// ---------------- mean-aggregate, XCD-sliced, group-per-node, 8-wide -------
// slice s = blockIdx&7 -> XCD s; per-XCD table slice 3.2 MB is L2-resident
// (proven R2/R3: FETCH 257->47->85 MB incl. csr re-reads). R3 showed MLP=1
// per group chain (129 us, VALU 19%, everything idle). NEW: 8-wide edge
// batches -> 8 csr loads + 8 independent 32B gathers in flight per group;
// fully predicated 8-wide tail batch (group-uniform mask, exec-masked loads).
#define ACC2(v) do { \
    acc.x += bflo((v).x); acc.y += bfhi((v).x); \
    acc.z += bflo((v).y); acc.w += bfhi((v).y); } while (0)

__global__ __launch_bounds__(256) void k_aggb(const unsigned short* __restrict__ featS,
                                              const int* __restrict__ offs,
                                              const int* __restrict__ csr,
                                              const float* __restrict__ dinv,
                                              unsigned short* __restrict__ outS, int n) {
    const int s = blockIdx.x & 7;
    const int wslot = (blockIdx.x >> 3) * 4 + (threadIdx.x >> 6);
    const int lane = threadIdx.x & 63;
    const int g = lane >> 2;   // group 0..15, one node each
    const int q = lane & 3;    // uint2 within 32B row (4 channels)
    const uint2* fS = (const uint2*)featS + (size_t)s * n * 4;
    uint2* oS = (uint2*)outS + (size_t)s * n * 4;

    const int node = wslot * 16 + g;
    if (wslot * 16 >= n) return;
    const bool valid = node < n;
    const int beg = valid ? offs[node] : 0;
    const int end = valid ? offs[node + 1] : 0;
    f32x4 acc = (f32x4){0.f, 0.f, 0.f, 0.f};

    int e = beg;
    // main: 8 edges per iteration, all loads independent
    for (; e + 8 <= end; e += 8) {
        int s0 = csr[e],     s1 = csr[e + 1], s2 = csr[e + 2], s3 = csr[e + 3];
        int s4 = csr[e + 4], s5 = csr[e + 5], s6 = csr[e + 6], s7 = csr[e + 7];
        uint2 v0 = fS[(unsigned)s0 * 4u + q];
        uint2 v1 = fS[(unsigned)s1 * 4u + q];
        uint2 v2 = fS[(unsigned)s2 * 4u + q];
        uint2 v3 = fS[(unsigned)s3 * 4u + q];
        uint2 v4 = fS[(unsigned)s4 * 4u + q];
        uint2 v5 = fS[(unsigned)s5 * 4u + q];
        uint2 v6 = fS[(unsigned)s6 * 4u + q];
        uint2 v7 = fS[(unsigned)s7 * 4u + q];
        ACC2(v0); ACC2(v1); ACC2(v2); ACC2(v3);
        ACC2(v4); ACC2(v5); ACC2(v6); ACC2(v7);
    }
    // predicated tail batch: remaining 0..7 edges, loads exec-masked,
    // zero-fill keeps accumulation unconditional, all loads independent
    {
        uint2 t0 = make_uint2(0u, 0u), t1 = t0, t2 = t0, t3 = t0;
        uint2 t4 = t0, t5 = t0, t6 = t0, t7 = t0;
        if (e     < end) t0 = fS[(unsigned)csr[e]     * 4u + q];
        if (e + 1 < end) t1 = fS[(unsigned)csr[e + 1] * 4u + q];
        if (e + 2 < end) t2 = fS[(unsigned)csr[e + 2] * 4u + q];
        if (e + 3 < end) t3 = fS[(unsigned)csr[e + 3] * 4u + q];
        if (e + 4 < end) t4 = fS[(unsigned)csr[e + 4] * 4u + q];
        if (e + 5 < end) t5 = fS[(unsigned)csr[e + 5] * 4u + q];
        if (e + 6 < end) t6 = fS[(unsigned)csr[e + 6] * 4u + q];
        if (e + 7 < end) t7 = fS[(unsigned)csr[e + 7] * 4u + q];
        ACC2(t0); ACC2(t1); ACC2(t2); ACC2(t3);
        ACC2(t4); ACC2(t5); ACC2(t6); ACC2(t7);
    }

    if (valid) {
        float di = dinv[node];
        uint2 o;
        o.x = (unsigned)f2bf(acc.x * di) | ((unsigned)f2bf(acc.y * di) << 16);
        o.y = (unsigned)f2bf(acc.z * di) | ((unsigned)f2bf(acc.w * di) << 16);
        oS[(size_t)node * 4 + q] = o;
    }
}

// ---------------- MFMA GEMM (+optional fused head), slice-major A ----------
template <int NT, int KCH, bool TWO, bool RELU, bool RESID, bool HEAD, bool OUTBF>
__global__ __launch_bounds__(256) void k_mfma(const unsigned short* __restrict__ P,
                                              const unsigned short* __restrict__ Q,
                                              const unsigned short* __restrict__ Wp,
                                              const float* __restrict__ bias,
                                              const unsigned short* __restrict__ resid,
                                              const unsigned short* __restrict__ Wp2,
                                              const float* __restrict__ bias2,
                                              void* __restrict__ outv, int n) {
    const int lane = threadIdx.x & 63;
    const int wave = threadIdx.x >> 6;
    const int quad = lane >> 4;
    const int row0 = blockIdx.x * 64 + wave * 16;
    int rowA = row0 + (lane & 15);
    if (rowA >= n) rowA = n - 1;

    f32x4 acc[NT];
#pragma unroll
    for (int t = 0; t < NT; t++) acc[t] = (f32x4){0.f, 0.f, 0.f, 0.f};

#pragma unroll
    for (int c = 0; c < KCH; c++) {
        const unsigned short* Abase = (TWO && c >= KCH / 2) ? Q : P;
        const int kk = (TWO ? (c & (KCH / 2 - 1)) : c) * 32 + quad * 8;
        // slice-major: channel kk -> slice kk>>4, offset kk&15
        bf16x8 a = *(const bf16x8*)&Abase[((size_t)(kk >> 4) * NND + rowA) * 16 + (kk & 15)];
#pragma unroll
        for (int t = 0; t < NT; t++) {
            bf16x8 b = *(const bf16x8*)&Wp[(size_t)((c * NT + t) * 64 + lane) * 8];
            acc[t] = __builtin_amdgcn_mfma_f32_16x16x32_bf16(a, b, acc[t], 0, 0, 0);
        }
    }

    const int col = lane & 15;
    if (!HEAD) {
#pragma unroll
        for (int t = 0; t < NT; t++) {
            float bv = bias[t * 16 + col];
#pragma unroll
            for (int r = 0; r < 4; r++) {
                int row = row0 + quad * 4 + r;
                if (row < n) {
                    float v = acc[t][r] + bv;
                    if (RESID) v += bf1(resid[((size_t)t * NND + row) * 16 + col]);
                    if (RELU) v = fmaxf(v, 0.f);
                    if (OUTBF)  // slice-major: output slice = t
                        ((unsigned short*)outv)[((size_t)t * NND + row) * 16 + col] = f2bf(v);
                    else
                        ((float*)outv)[(size_t)row * (NT * 16) + t * 16 + col] = v;
                }
            }
        }
    } else {
        __shared__ __align__(16) unsigned short sT[4][16 * 136];
#pragma unroll
        for (int t = 0; t < NT; t++) {
            float bv = bias[t * 16 + col];
#pragma unroll
            for (int r = 0; r < 4; r++) {
                int row = row0 + quad * 4 + r;
                int rr = row < n ? row : n - 1;
                float v = acc[t][r] + bv;
                if (RESID) v += bf1(resid[((size_t)t * NND + rr) * 16 + col]);
                if (RELU) v = fmaxf(v, 0.f);
                sT[wave][(quad * 4 + r) * 136 + t * 16 + col] = f2bf(v);
            }
        }
        f32x4 hacc[4];
#pragma unroll
        for (int t = 0; t < 4; t++) hacc[t] = (f32x4){0.f, 0.f, 0.f, 0.f};
#pragma unroll
        for (int c = 0; c < 4; c++) {
            bf16x8 a = *(const bf16x8*)&sT[wave][(lane & 15) * 136 + c * 32 + quad * 8];
#pragma unroll
            for (int t = 0; t < 4; t++) {
                bf16x8 b = *(const bf16x8*)&Wp2[(size_t)((c * 4 + t) * 64 + lane) * 8];
                hacc[t] = __builtin_amdgcn_mfma_f32_16x16x32_bf16(a, b, hacc[t], 0, 0, 0);
            }
        }
#pragma unroll
        for (int t = 0; t < 4; t++) {
            float bv = bias2[t * 16 + col];
#pragma unroll
            for (int r = 0; r < 4; r++) {
                int row = row0 + quad * 4 + r;
                if (row < n)
                    ((float*)outv)[(size_t)row * 64 + t * 16 + col] = hacc[t][r] + bv;
            }
        }
    }
}

extern "C" void kernel_launch(void* const* d_in, const int* in_sizes, int n_in,
                              void* d_out, int out_size, void* d_ws, size_t ws_size,
                              hipStream_t stream) {
    const float* x    = (const float*)d_in[0];
    const int*   ei   = (const int*)d_in[1];
    const float* W1l  = (const float*)d_in[2];
    const float* b1   = (const float*)d_in[3];
    const float* W1r  = (const float*)d_in[4];
    const float* W2l  = (const float*)d_in[5];
    const float* b2   = (const float*)d_in[6];
    const float* W2r  = (const float*)d_in[7];
    const float* Wlin = (const float*)d_in[8];
    const float* blin = (const float*)d_in[9];
    float* out = (float*)d_out;

    const int N = NND, E = NED;
    const int* src = ei;
    const int* dst = ei + E;
    const int NB2 = HTN / 1024;  // 128 scan blocks

    char* w = (char*)d_ws;
    int*   histT  = (int*)w;               w += (size_t)HTN * 4;
    int*   sh     = (int*)w;               w += (size_t)HTN * 4;
    int*   psum   = (int*)w;               w += (size_t)NB2 * 4;
    int*   offs   = (int*)w;               w += (size_t)(N + 4) * 4;
    float* dinv   = (float*)w;             w += (size_t)N * 4;
    uint2* eS     = (uint2*)w;             w += (size_t)E * 8;
    int*   csr    = (int*)w;               w += (size_t)E * 4;
    unsigned short* p1  = (unsigned short*)w;  w += 256 * 128 * 2;
    unsigned short* p2  = (unsigned short*)w;  w += 256 * 128 * 2;
    unsigned short* ph  = (unsigned short*)w;  w += 128 * 64 * 2;
    unsigned short* xb  = (unsigned short*)w;  w += (size_t)N * 128 * 2;
    unsigned short* agg = (unsigned short*)w;  w += (size_t)N * 128 * 2;
    unsigned short* h1  = (unsigned short*)w;  w += (size_t)N * 128 * 2;

    // CSR build: zero global atomics
    k_hist_cast<<<NBLK, 256, 0, stream>>>(dst, histT, x, (unsigned int*)xb,
                                          W1l, W1r, W2l, W2r, Wlin, p1, p2, ph);
    g_scan1<<<NB2, 1024, 0, stream>>>(histT, psum, HTN);
    g_scan2<<<1, 128, 0, stream>>>(psum, NB2);
    g_scan3<<<NB2, 1024, 0, stream>>>(histT, psum, sh, HTN);
    k_scatter<<<NBLK, 256, 0, stream>>>(src, dst, sh, eS);
    k_bucket<<<NBUCK, 1024, 0, stream>>>(eS, sh, csr, offs, dinv, N);

    // layer 1: h1 = relu([agg|xb] @ [W1l;W1r] + b1)
    k_aggb<<<AGGCH * 8, 256, 0, stream>>>(xb, offs, csr, dinv, agg, N);
    k_mfma<8, 8, true, true, false, false, true><<<(N + 63) / 64, 256, 0, stream>>>(
        agg, xb, p1, b1, nullptr, nullptr, nullptr, h1, N);

    // layer 2 + head fused
    k_aggb<<<AGGCH * 8, 256, 0, stream>>>(h1, offs, csr, dinv, agg, N);
    k_mfma<8, 8, true, true, true, true, false><<<(N + 63) / 64, 256, 0, stream>>>(
        agg, h1, p2, b2, h1, ph, blin, out, N);
}

// Round 5
// 382.016 us; speedup vs baseline: 1.5129x; 1.0562x over previous
//
#include <hip/hip_runtime.h>
#include <hip/hip_bf16.h>
#include <cstdint>

#define NND 100000
#define NED 1600000
#define FIN 128
#define FOUT 64

// bucket-sort CSR parameters
#define NBLK 512              // histogram/scatter blocks
#define EPB (NED / NBLK)      // 3125 edges per block (exact)
#define NBUCK 256             // coarse buckets
#define BSH 9                 // bucket = dst >> 9
#define BNODES 512            // nodes per bucket
#define HTN (NBUCK * NBLK)    // histT length = 131072

// feature-slice parameters: 4 slices of 32 channels; slice s -> XCDs {s,s+4}
// layout: feat[slice][node][32ch] bf16 (64 B per node-slice row)
#define NSLICE 4
#define NPW 8                 // nodes per wave (8 groups x 8 lanes)
#define AGGB_BLK (NSLICE * (NND / (NPW * 4)))   // 4 * 3125 = 12500 blocks
#define EMAX 512              // LDS-staged edge ids per wave

typedef __bf16 bf16x8 __attribute__((ext_vector_type(8)));
typedef float f32x4 __attribute__((ext_vector_type(4)));

static __device__ inline unsigned short f2bf(float f) {
    unsigned int u = __builtin_bit_cast(unsigned int, f);
    unsigned int r = (u + 0x7fffu + ((u >> 16) & 1u)) >> 16;  // RNE
    return (unsigned short)r;
}
static __device__ inline float bflo(unsigned int v) {
    return __builtin_bit_cast(float, v << 16);
}
static __device__ inline float bfhi(unsigned int v) {
    return __builtin_bit_cast(float, v & 0xffff0000u);
}
static __device__ inline float bf1(unsigned short u) {
    return __builtin_bit_cast(float, (unsigned int)u << 16);
}

// ---------------- weight pack into MFMA B-fragment order ----------------
static __device__ inline void pack_one(const float* __restrict__ W,
                                       unsigned short* __restrict__ out,
                                       int NTtot, int c_local, int nt,
                                       int chunkOff, int ncols, int lane) {
    int k = c_local * 32 + (lane >> 4) * 8;
    int n = nt * 16 + (lane & 15);
    unsigned short t[8];
#pragma unroll
    for (int j = 0; j < 8; j++) t[j] = f2bf(W[(size_t)(k + j) * ncols + n]);
    uint4 u;
    u.x = t[0] | ((unsigned)t[1] << 16);
    u.y = t[2] | ((unsigned)t[3] << 16);
    u.z = t[4] | ((unsigned)t[5] << 16);
    u.w = t[6] | ((unsigned)t[7] << 16);
    *(uint4*)&out[((size_t)((c_local + chunkOff) * NTtot + nt) * 64 + lane) * 8] = u;
}

// ---------------- K1: per-block bucket histogram + x cast + weight pack ----
// cast writes SLICE-MAJOR xb: xb[(s*N + node)*32 + ch32]
__global__ __launch_bounds__(256) void k_hist_cast(
        const int* __restrict__ dst, int* __restrict__ histT,
        const float* __restrict__ x, unsigned int* __restrict__ xb,
        const float* W1l, const float* W1r, const float* W2l,
        const float* W2r, const float* Wlin,
        unsigned short* p1, unsigned short* p2, unsigned short* ph) {
    __shared__ int hist[NBUCK];
    const int tid = threadIdx.x, blk = blockIdx.x;
    hist[tid] = 0;  // 256 threads == NBUCK
    __syncthreads();
    const int e0 = blk * EPB, e1 = e0 + EPB;
    for (int i = e0 + tid; i < e1; i += 256)
        atomicAdd(&hist[dst[i] >> BSH], 1);   // LDS atomic
    __syncthreads();
    histT[tid * NBLK + blk] = hist[tid];
    // fused weight pack (blocks 0..143, first wave)
    if (blk < 144 && tid < 64) {
        int b = blk, lane = tid;
        if (b < 32)       pack_one(W1l, p1, 8, b >> 3, b & 7, 0, 128, lane);
        else if (b < 64)  { b -= 32; pack_one(W1r, p1, 8, b >> 3, b & 7, 4, 128, lane); }
        else if (b < 96)  { b -= 64; pack_one(W2l, p2, 8, b >> 3, b & 7, 0, 128, lane); }
        else if (b < 128) { b -= 96; pack_one(W2r, p2, 8, b >> 3, b & 7, 4, 128, lane); }
        else              { b -= 128; pack_one(Wlin, ph, 4, b >> 2, b & 3, 0, 64, lane); }
    }
    // fused cast: j = (s*N + node)*8 + part  (uint2 = 4 channels; 8 per row)
    const int total = NND * 32;
    for (int j = blk * 256 + tid; j < total; j += NBLK * 256) {
        int sNode = j >> 3;
        int part = j & 7;
        int s = sNode / NND;
        int node = sNode - s * NND;
        float4 v = ((const float4*)x)[node * 32 + s * 8 + part];
        uint2 o;
        o.x = (unsigned)f2bf(v.x) | ((unsigned)f2bf(v.y) << 16);
        o.y = (unsigned)f2bf(v.z) | ((unsigned)f2bf(v.w) << 16);
        ((uint2*)xb)[j] = o;
    }
}

// ---------------- generic hierarchical exclusive scan (n = HTN) ------------
__global__ __launch_bounds__(1024) void g_scan1(const int* __restrict__ in,
                                                int* __restrict__ psum, int n) {
    __shared__ int red[1024];
    int tid = threadIdx.x;
    int i = blockIdx.x * 1024 + tid;
    red[tid] = (i < n) ? in[i] : 0;
    __syncthreads();
#pragma unroll
    for (int off = 512; off > 0; off >>= 1) {
        if (tid < off) red[tid] += red[tid + off];
        __syncthreads();
    }
    if (tid == 0) psum[blockIdx.x] = red[0];
}

__global__ __launch_bounds__(128) void g_scan2(int* __restrict__ psum, int nb) {
    int tid = threadIdx.x;
    int d = (tid < nb) ? psum[tid] : 0;
    int v = d;
#pragma unroll
    for (int off = 1; off < 64; off <<= 1) {
        int u = __shfl_up(v, off, 64);
        if ((tid & 63) >= off) v += u;
    }
    __shared__ int ws[2];
    if ((tid & 63) == 63) ws[tid >> 6] = v;
    __syncthreads();
    int base = (tid >= 64) ? ws[0] : 0;
    if (tid < nb) psum[tid] = base + v - d;
}

__global__ __launch_bounds__(1024) void g_scan3(const int* __restrict__ in,
                                                const int* __restrict__ psum,
                                                int* __restrict__ out, int n) {
    int tid = threadIdx.x;
    int i = blockIdx.x * 1024 + tid;
    int d = (i < n) ? in[i] : 0;
    int v = d;
#pragma unroll
    for (int off = 1; off < 64; off <<= 1) {
        int u = __shfl_up(v, off, 64);
        if ((tid & 63) >= off) v += u;
    }
    __shared__ int wsum[16];
    int wid = tid >> 6;
    if ((tid & 63) == 63) wsum[wid] = v;
    __syncthreads();
    if (tid < 16) {
        int w = wsum[tid];
#pragma unroll
        for (int off = 1; off < 16; off <<= 1) {
            int u = __shfl_up(w, off, 64);
            if (tid >= off) w += u;
        }
        wsum[tid] = w;
    }
    __syncthreads();
    int base = psum[blockIdx.x] + (wid ? wsum[wid - 1] : 0);
    if (i < n) out[i] = base + v - d;
}

// ---------------- K3: coarse scatter into bucket-grouped pairs -------------
__global__ __launch_bounds__(256) void k_scatter(const int* __restrict__ src,
                                                 const int* __restrict__ dst,
                                                 const int* __restrict__ sh,
                                                 uint2* __restrict__ eS) {
    __shared__ int cur[NBUCK];
    const int tid = threadIdx.x, blk = blockIdx.x;
    cur[tid] = sh[tid * NBLK + blk];
    __syncthreads();
    const int e0 = blk * EPB, e1 = e0 + EPB;
    for (int i = e0 + tid; i < e1; i += 256) {
        int d = dst[i];
        int pos = atomicAdd(&cur[d >> BSH], 1);   // LDS atomic
        eS[pos] = make_uint2((unsigned)src[i], (unsigned)(d & (BNODES - 1)));
    }
}

// ---------------- K4: per-bucket counting sort -> csr, offs, dinv ----------
__global__ __launch_bounds__(1024) void k_bucket(const uint2* __restrict__ eS,
                                                 const int* __restrict__ sh,
                                                 int* __restrict__ csr,
                                                 int* __restrict__ offs,
                                                 float* __restrict__ dinv, int n) {
    __shared__ int cnt[BNODES];
    __shared__ int loc[BNODES];
    const int b = blockIdx.x, tid = threadIdx.x;
    const int base = sh[b * NBLK];
    const int end = (b == NBUCK - 1) ? NED : sh[(b + 1) * NBLK];
    if (tid < BNODES) cnt[tid] = 0;
    __syncthreads();
    for (int i = base + tid; i < end; i += 1024)
        atomicAdd(&cnt[eS[i].y], 1);              // LDS atomic
    __syncthreads();
    // inclusive Hillis-Steele scan of cnt -> loc
    if (tid < BNODES) loc[tid] = cnt[tid];
    __syncthreads();
#pragma unroll
    for (int off = 1; off < BNODES; off <<= 1) {
        int v = 0;
        if (tid < BNODES && tid >= off) v = loc[tid - off];
        __syncthreads();
        if (tid < BNODES) loc[tid] += v;
        __syncthreads();
    }
    int node = b * BNODES + tid;
    int myExcl = 0;
    if (tid < BNODES) {
        myExcl = loc[tid] - cnt[tid];  // exclusive
        if (node < n) {
            offs[node] = base + myExcl;
            dinv[node] = 1.0f / fmaxf((float)cnt[tid], 1.0f);
        }
    }
    __syncthreads();
    if (tid < BNODES) cnt[tid] = base + myExcl;  // running cursor
    __syncthreads();
    for (int i = base + tid; i < end; i += 1024) {
        uint2 e = eS[i];
        int slot = atomicAdd(&cnt[e.y], 1);       // LDS atomic
        csr[slot] = (int)e.x;
    }
    if (b == 0 && tid == 0) offs[n] = NED;
}

// ---------------- mean-aggregate: 4-slice XCD-affine, LDS-staged csr -------
// slice = blockIdx&3 (XCDs {s,s+4}); 64B rows halve gather line-visits vs
// 16ch slices (R4: TA request-rate bound at 12.8M+12.8M line-visits). csr
// staged through LDS coalesced (4 lines/instr) -> csr request tax ~gone.
// 8 groups of 8 lanes; group g owns node base+g; 8 gathers in flight.
#define ACC2(v) do { \
    acc.x += bflo((v).x); acc.y += bfhi((v).x); \
    acc.z += bflo((v).y); acc.w += bfhi((v).y); } while (0)

__global__ __launch_bounds__(256) void k_aggb(const unsigned short* __restrict__ featS,
                                              const int* __restrict__ offs,
                                              const int* __restrict__ csr,
                                              const float* __restrict__ dinv,
                                              unsigned short* __restrict__ outS, int n) {
    __shared__ int eids[4][EMAX];
    const int s = blockIdx.x & 3;
    const int wv = threadIdx.x >> 6;
    const int wslot = (blockIdx.x >> 2) * 4 + wv;
    const int lane = threadIdx.x & 63;
    const int g = lane >> 3;   // group 0..7, one node each
    const int q = lane & 7;    // uint2 (4ch) within 64B row
    const uint2* fS = (const uint2*)featS + (size_t)s * n * 8;
    uint2* oS = (uint2*)outS + (size_t)s * n * 8;

    const int base = wslot * NPW;
    const int node = base + g;
    const bool valid = node < n;
    const int nc = valid ? node : n - 1;
    const int beg = offs[nc];
    const int end = offs[nc + 1];
    // wave's full csr range (lane0 = first node, lane63 = last node)
    const int begW = __shfl(beg, 0);
    const int endW = __shfl(end, 63);
    const int lim = min(endW - begW, EMAX);
    for (int i = lane; i < lim; i += 64)
        eids[wv][i] = csr[begW + i];
    __syncthreads();

    f32x4 acc = (f32x4){0.f, 0.f, 0.f, 0.f};
    const int deg = valid ? (end - beg) : 0;
    const int lb = beg - begW;

    int j = 0;
    for (; j + 8 <= deg; j += 8) {
        int i0, i1, i2, i3, i4, i5, i6, i7;
        if (lb + j + 8 <= EMAX) {
            i0 = eids[wv][lb + j];     i1 = eids[wv][lb + j + 1];
            i2 = eids[wv][lb + j + 2]; i3 = eids[wv][lb + j + 3];
            i4 = eids[wv][lb + j + 4]; i5 = eids[wv][lb + j + 5];
            i6 = eids[wv][lb + j + 6]; i7 = eids[wv][lb + j + 7];
        } else {  // near-impossible overflow fallback
            i0 = csr[beg + j];     i1 = csr[beg + j + 1];
            i2 = csr[beg + j + 2]; i3 = csr[beg + j + 3];
            i4 = csr[beg + j + 4]; i5 = csr[beg + j + 5];
            i6 = csr[beg + j + 6]; i7 = csr[beg + j + 7];
        }
        uint2 v0 = fS[(unsigned)i0 * 8u + q];
        uint2 v1 = fS[(unsigned)i1 * 8u + q];
        uint2 v2 = fS[(unsigned)i2 * 8u + q];
        uint2 v3 = fS[(unsigned)i3 * 8u + q];
        uint2 v4 = fS[(unsigned)i4 * 8u + q];
        uint2 v5 = fS[(unsigned)i5 * 8u + q];
        uint2 v6 = fS[(unsigned)i6 * 8u + q];
        uint2 v7 = fS[(unsigned)i7 * 8u + q];
        ACC2(v0); ACC2(v1); ACC2(v2); ACC2(v3);
        ACC2(v4); ACC2(v5); ACC2(v6); ACC2(v7);
    }
    // predicated tail batch (0..7 edges), zero-fill, loads exec-masked
    {
        uint2 t0 = make_uint2(0u, 0u), t1 = t0, t2 = t0, t3 = t0;
        uint2 t4 = t0, t5 = t0, t6 = t0, t7 = t0;
#define TAIL(K, TV) do { \
        if (j + K < deg) { \
            int li = lb + j + K; \
            int id = (li < EMAX) ? eids[wv][li] : csr[begW + li]; \
            TV = fS[(unsigned)id * 8u + q]; \
        } } while (0)
        TAIL(0, t0); TAIL(1, t1); TAIL(2, t2); TAIL(3, t3);
        TAIL(4, t4); TAIL(5, t5); TAIL(6, t6); TAIL(7, t7);
#undef TAIL
        ACC2(t0); ACC2(t1); ACC2(t2); ACC2(t3);
        ACC2(t4); ACC2(t5); ACC2(t6); ACC2(t7);
    }

    if (valid) {
        float di = dinv[node];
        uint2 o;
        o.x = (unsigned)f2bf(acc.x * di) | ((unsigned)f2bf(acc.y * di) << 16);
        o.y = (unsigned)f2bf(acc.z * di) | ((unsigned)f2bf(acc.w * di) << 16);
        oS[(size_t)node * 8 + q] = o;
    }
}

// ---------------- MFMA GEMM (+optional fused head), 4-slice-major A --------
template <int NT, int KCH, bool TWO, bool RELU, bool RESID, bool HEAD, bool OUTBF>
__global__ __launch_bounds__(256) void k_mfma(const unsigned short* __restrict__ P,
                                              const unsigned short* __restrict__ Q,
                                              const unsigned short* __restrict__ Wp,
                                              const float* __restrict__ bias,
                                              const unsigned short* __restrict__ resid,
                                              const unsigned short* __restrict__ Wp2,
                                              const float* __restrict__ bias2,
                                              void* __restrict__ outv, int n) {
    const int lane = threadIdx.x & 63;
    const int wave = threadIdx.x >> 6;
    const int quad = lane >> 4;
    const int row0 = blockIdx.x * 64 + wave * 16;
    int rowA = row0 + (lane & 15);
    if (rowA >= n) rowA = n - 1;

    f32x4 acc[NT];
#pragma unroll
    for (int t = 0; t < NT; t++) acc[t] = (f32x4){0.f, 0.f, 0.f, 0.f};

#pragma unroll
    for (int c = 0; c < KCH; c++) {
        const unsigned short* Abase = (TWO && c >= KCH / 2) ? Q : P;
        const int kk = (TWO ? (c & (KCH / 2 - 1)) : c) * 32 + quad * 8;
        // 4-slice-major: channel kk -> slice kk>>5, offset kk&31
        bf16x8 a = *(const bf16x8*)&Abase[((size_t)(kk >> 5) * NND + rowA) * 32 + (kk & 31)];
#pragma unroll
        for (int t = 0; t < NT; t++) {
            bf16x8 b = *(const bf16x8*)&Wp[(size_t)((c * NT + t) * 64 + lane) * 8];
            acc[t] = __builtin_amdgcn_mfma_f32_16x16x32_bf16(a, b, acc[t], 0, 0, 0);
        }
    }

    const int col = lane & 15;
    if (!HEAD) {
#pragma unroll
        for (int t = 0; t < NT; t++) {
            float bv = bias[t * 16 + col];
#pragma unroll
            for (int r = 0; r < 4; r++) {
                int row = row0 + quad * 4 + r;
                if (row < n) {
                    float v = acc[t][r] + bv;
                    if (RESID) v += bf1(resid[((size_t)(t >> 1) * NND + row) * 32 + (t & 1) * 16 + col]);
                    if (RELU) v = fmaxf(v, 0.f);
                    if (OUTBF)  // 4-slice-major: out channel t*16+col -> slice t>>1
                        ((unsigned short*)outv)[((size_t)(t >> 1) * NND + row) * 32 + (t & 1) * 16 + col] = f2bf(v);
                    else
                        ((float*)outv)[(size_t)row * (NT * 16) + t * 16 + col] = v;
                }
            }
        }
    } else {
        __shared__ __align__(16) unsigned short sT[4][16 * 136];
#pragma unroll
        for (int t = 0; t < NT; t++) {
            float bv = bias[t * 16 + col];
#pragma unroll
            for (int r = 0; r < 4; r++) {
                int row = row0 + quad * 4 + r;
                int rr = row < n ? row : n - 1;
                float v = acc[t][r] + bv;
                if (RESID) v += bf1(resid[((size_t)(t >> 1) * NND + rr) * 32 + (t & 1) * 16 + col]);
                if (RELU) v = fmaxf(v, 0.f);
                sT[wave][(quad * 4 + r) * 136 + t * 16 + col] = f2bf(v);
            }
        }
        f32x4 hacc[4];
#pragma unroll
        for (int t = 0; t < 4; t++) hacc[t] = (f32x4){0.f, 0.f, 0.f, 0.f};
#pragma unroll
        for (int c = 0; c < 4; c++) {
            bf16x8 a = *(const bf16x8*)&sT[wave][(lane & 15) * 136 + c * 32 + quad * 8];
#pragma unroll
            for (int t = 0; t < 4; t++) {
                bf16x8 b = *(const bf16x8*)&Wp2[(size_t)((c * 4 + t) * 64 + lane) * 8];
                hacc[t] = __builtin_amdgcn_mfma_f32_16x16x32_bf16(a, b, hacc[t], 0, 0, 0);
            }
        }
#pragma unroll
        for (int t = 0; t < 4; t++) {
            float bv = bias2[t * 16 + col];
#pragma unroll
            for (int r = 0; r < 4; r++) {
                int row = row0 + quad * 4 + r;
                if (row < n)
                    ((float*)outv)[(size_t)row * 64 + t * 16 + col] = hacc[t][r] + bv;
            }
        }
    }
}

extern "C" void kernel_launch(void* const* d_in, const int* in_sizes, int n_in,
                              void* d_out, int out_size, void* d_ws, size_t ws_size,
                              hipStream_t stream) {
    const float* x    = (const float*)d_in[0];
    const int*   ei   = (const int*)d_in[1];
    const float* W1l  = (const float*)d_in[2];
    const float* b1   = (const float*)d_in[3];
    const float* W1r  = (const float*)d_in[4];
    const float* W2l  = (const float*)d_in[5];
    const float* b2   = (const float*)d_in[6];
    const float* W2r  = (const float*)d_in[7];
    const float* Wlin = (const float*)d_in[8];
    const float* blin = (const float*)d_in[9];
    float* out = (float*)d_out;

    const int N = NND, E = NED;
    const int* src = ei;
    const int* dst = ei + E;
    const int NB2 = HTN / 1024;  // 128 scan blocks

    char* w = (char*)d_ws;
    int*   histT  = (int*)w;               w += (size_t)HTN * 4;
    int*   sh     = (int*)w;               w += (size_t)HTN * 4;
    int*   psum   = (int*)w;               w += (size_t)NB2 * 4;
    int*   offs   = (int*)w;               w += (size_t)(N + 4) * 4;
    float* dinv   = (float*)w;             w += (size_t)N * 4;
    uint2* eS     = (uint2*)w;             w += (size_t)E * 8;
    int*   csr    = (int*)w;               w += (size_t)E * 4;
    unsigned short* p1  = (unsigned short*)w;  w += 256 * 128 * 2;
    unsigned short* p2  = (unsigned short*)w;  w += 256 * 128 * 2;
    unsigned short* ph  = (unsigned short*)w;  w += 128 * 64 * 2;
    unsigned short* xb  = (unsigned short*)w;  w += (size_t)N * 128 * 2;
    unsigned short* agg = (unsigned short*)w;  w += (size_t)N * 128 * 2;
    unsigned short* h1  = (unsigned short*)w;  w += (size_t)N * 128 * 2;

    // CSR build: zero global atomics
    k_hist_cast<<<NBLK, 256, 0, stream>>>(dst, histT, x, (unsigned int*)xb,
                                          W1l, W1r, W2l, W2r, Wlin, p1, p2, ph);
    g_scan1<<<NB2, 1024, 0, stream>>>(histT, psum, HTN);
    g_scan2<<<1, 128, 0, stream>>>(psum, NB2);
    g_scan3<<<NB2, 1024, 0, stream>>>(histT, psum, sh, HTN);
    k_scatter<<<NBLK, 256, 0, stream>>>(src, dst, sh, eS);
    k_bucket<<<NBUCK, 1024, 0, stream>>>(eS, sh, csr, offs, dinv, N);

    // layer 1: h1 = relu([agg|xb] @ [W1l;W1r] + b1)
    k_aggb<<<AGGB_BLK, 256, 0, stream>>>(xb, offs, csr, dinv, agg, N);
    k_mfma<8, 8, true, true, false, false, true><<<(N + 63) / 64, 256, 0, stream>>>(
        agg, xb, p1, b1, nullptr, nullptr, nullptr, h1, N);

    // layer 2 + head fused
    k_aggb<<<AGGB_BLK, 256, 0, stream>>>(h1, offs, csr, dinv, agg, N);
    k_mfma<8, 8, true, true, true, true, false><<<(N + 63) / 64, 256, 0, stream>>>(
        agg, h1, p2, b2, h1, ph, blin, out, N);
}